// Round 6
// baseline (926.411 us; speedup 1.0000x reference)
//
#include <hip/hip_runtime.h>

#define N_NODES 100000
#define N_EDGES 1600000
#define D 128
#define N_TILES 3125        // N_NODES / 32
#define GEMM_GRID 512
#define BK_NODES 256        // nodes per bucket
#define N_BUCKETS 391       // ceil(N_NODES / BK_NODES)

typedef _Float16 f16;
typedef _Float16 f16x8 __attribute__((ext_vector_type(8)));
typedef _Float16 f16x2 __attribute__((ext_vector_type(2)));
typedef float f32x4 __attribute__((ext_vector_type(4)));

// ---------------- CSR build ----------------

__global__ __launch_bounds__(256) void hist_kernel(const int* __restrict__ dst,
                                                   int* __restrict__ counts) {
    int e = blockIdx.x * 256 + threadIdx.x;   // grid exactly N_EDGES
    atomicAdd(&counts[dst[e]], 1);
}

__global__ __launch_bounds__(256) void scanA(const int* __restrict__ counts,
                                             int* __restrict__ row_ptr,
                                             int* __restrict__ blockSums) {
    __shared__ int sc[256];
    int tid  = threadIdx.x;
    int base = blockIdx.x * 1024 + tid * 4;
    int v[4];
#pragma unroll
    for (int k = 0; k < 4; ++k) {
        int i = base + k;
        v[k] = (i < N_NODES) ? counts[i] : 0;
    }
    int s = v[0] + v[1] + v[2] + v[3];
    sc[tid] = s;
    __syncthreads();
    for (int off = 1; off < 256; off <<= 1) {
        int t = (tid >= off) ? sc[tid - off] : 0;
        __syncthreads();
        sc[tid] += t;
        __syncthreads();
    }
    int run = sc[tid] - s;
#pragma unroll
    for (int k = 0; k < 4; ++k) {
        int i = base + k;
        if (i < N_NODES) row_ptr[i] = run;
        run += v[k];
    }
    if (tid == 255) blockSums[blockIdx.x] = sc[255];
}

__global__ void scanB(int* blockSums, int nb) {
    if (threadIdx.x == 0 && blockIdx.x == 0) {
        int run = 0;
        for (int b = 0; b < nb; ++b) {
            int t = blockSums[b];
            blockSums[b] = run;
            run += t;
        }
    }
}

__global__ __launch_bounds__(256) void scanC(int* __restrict__ row_ptr,
                                             const int* __restrict__ blockSums) {
    int tid  = threadIdx.x;
    int base = blockIdx.x * 1024 + tid * 4;
    int add  = blockSums[blockIdx.x];
#pragma unroll
    for (int k = 0; k < 4; ++k) {
        int i = base + k;
        if (i < N_NODES) row_ptr[i] += add;
    }
    if (blockIdx.x == 0 && tid == 0) row_ptr[N_NODES] = N_EDGES;
}

// bucket cursors start at the bucket's CSR base (= row_ptr at bucket's first node)
__global__ __launch_bounds__(256) void init_bcur(const int* __restrict__ row_ptr,
                                                 int* __restrict__ bcur) {
    int b = blockIdx.x * 256 + threadIdx.x;
    if (b < N_BUCKETS) bcur[b] = row_ptr[b * BK_NODES];
}

// pass 1: append edges to dst-buckets (391 sequential frontiers, no write blowup)
__global__ __launch_bounds__(256) void bucket_scatter(const int* __restrict__ src,
                                                      const int* __restrict__ dst,
                                                      const float* __restrict__ w,
                                                      int* __restrict__ bcur,
                                                      int2* __restrict__ bkt) {
    int e = blockIdx.x * 256 + threadIdx.x;   // grid exactly N_EDGES
    int d = dst[e];
    unsigned wq = (unsigned)rintf(w[e] * 32767.0f);
    int p = atomicAdd(&bcur[d >> 8], 1);
    bkt[p] = make_int2(src[e], (int)(((unsigned)d << 15) | wq));
}

// pass 2: one block per bucket; LDS per-node cursors; dense contiguous csr writes.
// csr[p] = (src << 15) | wq
__global__ __launch_bounds__(256) void bucket_to_csr(const int* __restrict__ row_ptr,
                                                     const int2* __restrict__ bkt,
                                                     unsigned* __restrict__ csr) {
    __shared__ int rp_s[BK_NODES];
    __shared__ int cur[BK_NODES];
    int tid   = threadIdx.x;
    int node0 = blockIdx.x * BK_NODES;
    int nN    = N_NODES - node0; if (nN > BK_NODES) nN = BK_NODES;
    if (tid < nN) { rp_s[tid] = row_ptr[node0 + tid]; cur[tid] = 0; }
    __syncthreads();
    int beg  = row_ptr[node0];
    int endv = row_ptr[node0 + nN];
    for (int i = beg + tid; i < endv; i += 256) {
        int2 t = bkt[i];
        unsigned meta = (unsigned)t.y;
        int local = (int)(meta >> 15) - node0;
        int p = rp_s[local] + atomicAdd(&cur[local], 1);
        csr[p] = ((unsigned)t.x << 15) | (meta & 0x7fffu);
    }
}

// ---------------- fp32 -> f16 convert (x only, once) ----------------

__global__ __launch_bounds__(256) void cvt_f32_f16(const float* __restrict__ in,
                                                   f16* __restrict__ out) {
    int i = blockIdx.x * 256 + threadIdx.x;   // grid 6250: 8 elems/thread
    const float4* in4 = (const float4*)in;
    float4 a = in4[i * 2], b = in4[i * 2 + 1];
    f16x8 v;
    v[0] = (f16)a.x; v[1] = (f16)a.y; v[2] = (f16)a.z; v[3] = (f16)a.w;
    v[4] = (f16)b.x; v[5] = (f16)b.y; v[6] = (f16)b.z; v[7] = (f16)b.w;
    ((f16x8*)out)[i] = v;
}

// ---------------- weight pack: B-fragment layout, f16 ----------------
// Bp element ((ks*8 + ct)*64 + lane)*8 + e = W[j][k] with
// j = ct*16 + (lane&15), k = ks*32 + (lane>>4)*8 + e  (k<128 -> Wrel, else Wroot)

__global__ __launch_bounds__(256) void pack_weights(const float* __restrict__ Wrel,
                                                    const float* __restrict__ Wroot,
                                                    f16* __restrict__ Bp) {
    int idx = blockIdx.x * 256 + threadIdx.x;   // 32768 total -> 128 blocks
    int e = idx & 7, lane = (idx >> 3) & 63, ct = (idx >> 9) & 7, ks = idx >> 12;
    int j = ct * 16 + (lane & 15);
    int k = ks * 32 + (lane >> 4) * 8 + e;
    float w = (k < D) ? Wrel[j * D + k] : Wroot[j * D + (k - D)];
    Bp[idx] = (f16)w;
}

// ---------------- aggregation: one wave/node, readlane CSR, pinned 16-deep MLP ----

__global__ __launch_bounds__(256) void aggregate_kernel(const f16* __restrict__ h,
                                                        const int* __restrict__ row_ptr,
                                                        const unsigned* __restrict__ csr,
                                                        f16* __restrict__ agg) {
    int node = blockIdx.x * 4 + (threadIdx.x >> 6);   // grid*4 == N_NODES exactly
    int lane = threadIdx.x & 63;
    int li   = lane & 15;
    int beg = row_ptr[node], end = row_ptr[node + 1];
    const f16x2* h2 = (const f16x2*)h;   // lane covers channels 2l, 2l+1

    float ax0 = 0.f, ay0 = 0.f, ax1 = 0.f, ay1 = 0.f;

    int e = beg;
    for (; e + 16 <= end; e += 16) {
        // lanes 0-15 fetch 16 packed edges in one 64B load (quarters duplicate)
        unsigned pv = csr[e + li];
        __builtin_amdgcn_sched_barrier(0);
        f16x2 gv[16];
        float gw[16];
#pragma unroll
        for (int k = 0; k < 16; ++k) {
            unsigned s = __builtin_amdgcn_readlane(pv, k);   // uniform -> SGPR
            gw[k] = (float)(s & 0x7fffu) * (1.0f / 32767.0f);
            gv[k] = h2[(size_t)(s >> 15) * 64 + lane];       // saddr gather, 256B/wave
        }
        __builtin_amdgcn_sched_barrier(0);   // keep all 16 gathers in flight
#pragma unroll
        for (int k = 0; k < 16; ++k) {
            float vx = (float)gv[k][0], vy = (float)gv[k][1];
            if (k & 1) { ax1 = fmaf(gw[k], vx, ax1); ay1 = fmaf(gw[k], vy, ay1); }
            else       { ax0 = fmaf(gw[k], vx, ax0); ay0 = fmaf(gw[k], vy, ay0); }
        }
    }
    if (e < end) {   // masked tail chunk: clamped index, zeroed weights
        int rem = end - e;
        int idx = e + li, em1 = end - 1;
        idx = idx < em1 ? idx : em1;
        unsigned pv = csr[idx];
        __builtin_amdgcn_sched_barrier(0);
        f16x2 gv[16];
        float gw[16];
#pragma unroll
        for (int k = 0; k < 16; ++k) {
            unsigned s = __builtin_amdgcn_readlane(pv, k);
            gw[k] = (k < rem) ? (float)(s & 0x7fffu) * (1.0f / 32767.0f) : 0.f;
            gv[k] = h2[(size_t)(s >> 15) * 64 + lane];
        }
        __builtin_amdgcn_sched_barrier(0);
#pragma unroll
        for (int k = 0; k < 16; ++k) {
            float vx = (float)gv[k][0], vy = (float)gv[k][1];
            if (k & 1) { ax1 = fmaf(gw[k], vx, ax1); ay1 = fmaf(gw[k], vy, ay1); }
            else       { ax0 = fmaf(gw[k], vx, ax0); ay0 = fmaf(gw[k], vy, ay0); }
        }
    }
    f16x2 o;
    o[0] = (f16)(ax0 + ax1);
    o[1] = (f16)(ay0 + ay1);
    ((f16x2*)agg)[(size_t)node * 64 + lane] = o;
}

// ---------------- MFMA GEMM: out = [agg|h] @ Bp + bias (+ReLU) ----------------
// 256 thr = 4 waves (2 row x 2 col). Wave owns 16 rows x 64 cols.
// B-frags in registers. A (f16) staged in LDS, XOR-swizzled, double-buffered.
// FINAL=0: f16 out + ReLU.  FINAL=1: fp32 out, no ReLU.

template <int FINAL>
__global__ __launch_bounds__(256, 2) void gemm_mfma(const f16* __restrict__ agg,
                                                    const f16* __restrict__ h,
                                                    const f16x8* __restrict__ Bp,
                                                    const float* __restrict__ bias,
                                                    void* __restrict__ outp) {
    __shared__ f16 sA[2][32 * 256];   // 2 x 16 KB
    int tid  = threadIdx.x;
    int lane = tid & 63;
    int wid  = tid >> 6;
    int wrow = wid >> 1;              // rows [wrow*16, +16)
    int wcol = wid & 1;               // cols [wcol*64, +64)

    // B fragments: 8 k-steps x 4 col-tiles, loaded once (L2-hot)
    f16x8 breg[8][4];
#pragma unroll
    for (int ks = 0; ks < 8; ++ks)
#pragma unroll
        for (int c = 0; c < 4; ++c)
            breg[ks][c] = Bp[(ks * 8 + wcol * 4 + c) * 64 + lane];

    float bv[4];
#pragma unroll
    for (int c = 0; c < 4; ++c) bv[c] = bias[wcol * 64 + c * 16 + (lane & 15)];

    const uint4* a16 = (const uint4*)agg;   // 8 f16 per uint4; 16 chunks/row
    const uint4* h16 = (const uint4*)h;

    // prologue: stage first tile into buf 0 (1024 x 16B chunks, 4 iters)
    {
        int row0 = blockIdx.x * 32;
#pragma unroll
        for (int it = 0; it < 4; ++it) {
            int i = it * 256 + tid, r = i >> 5, c8 = i & 31;
            uint4 v = (c8 < 16) ? a16[(row0 + r) * 16 + c8]
                                : h16[(row0 + r) * 16 + (c8 - 16)];
            int o = (r * 256 + c8 * 8) ^ ((r & 7) << 3);
            *(uint4*)&sA[0][o] = v;
        }
    }
    __syncthreads();

    int buf = 0;
    for (int t = blockIdx.x; t < N_TILES; t += GEMM_GRID) {
        int  tn = t + GEMM_GRID;
        bool havenext = (tn < N_TILES);

        // issue next tile's global loads early (latency hides under MFMA)
        uint4 sreg[4];
        if (havenext) {
            int row0 = tn * 32;
#pragma unroll
            for (int it = 0; it < 4; ++it) {
                int i = it * 256 + tid, r = i >> 5, c8 = i & 31;
                sreg[it] = (c8 < 16) ? a16[(row0 + r) * 16 + c8]
                                     : h16[(row0 + r) * 16 + (c8 - 16)];
            }
        }

        // compute tile t from sA[buf]
        f32x4 acc[4] = {f32x4{0,0,0,0}, f32x4{0,0,0,0}, f32x4{0,0,0,0}, f32x4{0,0,0,0}};
        int arow = wrow * 16 + (lane & 15);
        int kg   = (lane >> 4) * 8;
#pragma unroll
        for (int ks = 0; ks < 8; ++ks) {
            int o = (arow * 256 + ks * 32 + kg) ^ ((arow & 7) << 3);
            f16x8 afrag = *(const f16x8*)&sA[buf][o];
#pragma unroll
            for (int c = 0; c < 4; ++c)
                acc[c] = __builtin_amdgcn_mfma_f32_16x16x32_f16(afrag, breg[ks][c],
                                                                acc[c], 0, 0, 0);
        }

        // epilogue: bias (+relu), store C  (C/D map: col=lane&15, row=(lane>>4)*4+r)
        {
            int row0 = t * 32;
#pragma unroll
            for (int c = 0; c < 4; ++c) {
                int col = wcol * 64 + c * 16 + (lane & 15);
#pragma unroll
                for (int r = 0; r < 4; ++r) {
                    int row = row0 + wrow * 16 + (lane >> 4) * 4 + r;
                    float o = acc[c][r] + bv[c];
                    if (FINAL) {
                        ((float*)outp)[(size_t)row * D + col] = o;
                    } else {
                        ((f16*)outp)[(size_t)row * D + col] = (f16)fmaxf(o, 0.f);
                    }
                }
            }
        }

        __syncthreads();   // all waves done reading sA[buf^1] (previous iter)
        if (havenext) {
#pragma unroll
            for (int it = 0; it < 4; ++it) {
                int i = it * 256 + tid, r = i >> 5, c8 = i & 31;
                int o = (r * 256 + c8 * 8) ^ ((r & 7) << 3);
                *(uint4*)&sA[buf ^ 1][o] = sreg[it];
            }
        }
        __syncthreads();
        buf ^= 1;
    }
}

// ---------------- launch ----------------

extern "C" void kernel_launch(void* const* d_in, const int* in_sizes, int n_in,
                              void* d_out, int out_size, void* d_ws, size_t ws_size,
                              hipStream_t stream) {
    const float* x  = (const float*)d_in[0];
    const float* ew = (const float*)d_in[1];
    const float* W_rel[3]  = {(const float*)d_in[2], (const float*)d_in[5], (const float*)d_in[8]};
    const float* W_root[3] = {(const float*)d_in[3], (const float*)d_in[6], (const float*)d_in[9]};
    const float* bias[3]   = {(const float*)d_in[4], (const float*)d_in[7], (const float*)d_in[10]};
    const int* esrc = (const int*)d_in[11];
    const int* edst = (const int*)d_in[12];

    char* ws = (char*)d_ws;
    f16*      agg16     = (f16*)     (ws);               // 25,600,000 B
    f16*      bufA      = (f16*)     (ws + 25600000);    // 25,600,000 B
    f16*      bufB      = (f16*)     (ws + 51200000);    // 25,600,000 B
    unsigned* csr       = (unsigned*)(ws + 76800000);    //  6,400,000 B
    int2*     bkt       = (int2*)    (ws + 83200000);    // 12,800,000 B
    int*      row_ptr   = (int*)     (ws + 96000000);    //    400,016 B
    int*      cnt       = (int*)     (ws + 96400016);    //    400,000 B
    int*      blockSums = (int*)     (ws + 96800016);    //        512 B
    int*      bcur      = (int*)     (ws + 96800528);    //      1,564 B
    f16*      Bp        = (f16*)     (ws + 96802092);    //    196,608 B

    // CSR build (reused by all 3 layers)
    hipMemsetAsync(cnt, 0, N_NODES * sizeof(int), stream);
    hist_kernel<<<N_EDGES / 256, 256, 0, stream>>>(edst, cnt);
    scanA<<<98, 256, 0, stream>>>(cnt, row_ptr, blockSums);
    scanB<<<1, 64, 0, stream>>>(blockSums, 98);
    scanC<<<98, 256, 0, stream>>>(row_ptr, blockSums);
    init_bcur<<<2, 256, 0, stream>>>(row_ptr, bcur);
    bucket_scatter<<<N_EDGES / 256, 256, 0, stream>>>(esrc, edst, ew, bcur, bkt);
    bucket_to_csr<<<N_BUCKETS, 256, 0, stream>>>(row_ptr, bkt, csr);

    // x -> f16, weight packs
    cvt_f32_f16<<<6250, 256, 0, stream>>>(x, bufA);
    for (int l = 0; l < 3; ++l)
        pack_weights<<<128, 256, 0, stream>>>(W_rel[l], W_root[l], Bp + l * 32768);

    // layer 0: bufA -> bufB (f16, relu)
    aggregate_kernel<<<N_NODES / 4, 256, 0, stream>>>(bufA, row_ptr, csr, agg16);
    gemm_mfma<0><<<GEMM_GRID, 256, 0, stream>>>(agg16, bufA, (const f16x8*)(Bp + 0 * 32768),
                                                bias[0], bufB);
    // layer 1: bufB -> bufA (f16, relu)
    aggregate_kernel<<<N_NODES / 4, 256, 0, stream>>>(bufB, row_ptr, csr, agg16);
    gemm_mfma<0><<<GEMM_GRID, 256, 0, stream>>>(agg16, bufB, (const f16x8*)(Bp + 1 * 32768),
                                                bias[1], bufA);
    // layer 2: bufA -> d_out (fp32, no relu)
    aggregate_kernel<<<N_NODES / 4, 256, 0, stream>>>(bufA, row_ptr, csr, agg16);
    gemm_mfma<1><<<GEMM_GRID, 256, 0, stream>>>(agg16, bufA, (const f16x8*)(Bp + 2 * 32768),
                                                bias[2], d_out);
}

// Round 7
// 391.721 us; speedup vs baseline: 2.3650x; 2.3650x over previous
//
#include <hip/hip_runtime.h>

#define N_NODES 100000
#define N_EDGES 1600000
#define D 128
#define N_TILES 3125        // N_NODES / 32
#define GEMM_GRID 512
#define BK_NODES 256        // nodes per bucket
#define N_BUCKETS 391       // ceil(N_NODES / BK_NODES)
#define SC_BLOCKS 128
#define EPB 12500           // edges per scatter block (N_EDGES / SC_BLOCKS)

typedef _Float16 f16;
typedef _Float16 f16x8 __attribute__((ext_vector_type(8)));
typedef _Float16 f16x2 __attribute__((ext_vector_type(2)));
typedef float f32x4 __attribute__((ext_vector_type(4)));

// ---------------- CSR build ----------------

__global__ __launch_bounds__(256) void hist_kernel(const int* __restrict__ dst,
                                                   int* __restrict__ counts) {
    int e = blockIdx.x * 256 + threadIdx.x;   // grid exactly N_EDGES
    atomicAdd(&counts[dst[e]], 1);
}

__global__ __launch_bounds__(256) void scanA(const int* __restrict__ counts,
                                             int* __restrict__ row_ptr,
                                             int* __restrict__ blockSums) {
    __shared__ int sc[256];
    int tid  = threadIdx.x;
    int base = blockIdx.x * 1024 + tid * 4;
    int v[4];
#pragma unroll
    for (int k = 0; k < 4; ++k) {
        int i = base + k;
        v[k] = (i < N_NODES) ? counts[i] : 0;
    }
    int s = v[0] + v[1] + v[2] + v[3];
    sc[tid] = s;
    __syncthreads();
    for (int off = 1; off < 256; off <<= 1) {
        int t = (tid >= off) ? sc[tid - off] : 0;
        __syncthreads();
        sc[tid] += t;
        __syncthreads();
    }
    int run = sc[tid] - s;
#pragma unroll
    for (int k = 0; k < 4; ++k) {
        int i = base + k;
        if (i < N_NODES) row_ptr[i] = run;
        run += v[k];
    }
    if (tid == 255) blockSums[blockIdx.x] = sc[255];
}

__global__ void scanB(int* blockSums, int nb) {
    if (threadIdx.x == 0 && blockIdx.x == 0) {
        int run = 0;
        for (int b = 0; b < nb; ++b) {
            int t = blockSums[b];
            blockSums[b] = run;
            run += t;
        }
    }
}

__global__ __launch_bounds__(256) void scanC(int* __restrict__ row_ptr,
                                             const int* __restrict__ blockSums) {
    int tid  = threadIdx.x;
    int base = blockIdx.x * 1024 + tid * 4;
    int add  = blockSums[blockIdx.x];
#pragma unroll
    for (int k = 0; k < 4; ++k) {
        int i = base + k;
        if (i < N_NODES) row_ptr[i] += add;
    }
    if (blockIdx.x == 0 && tid == 0) row_ptr[N_NODES] = N_EDGES;
}

// bucket cursors start at the bucket's CSR base (= row_ptr at bucket's first node)
__global__ __launch_bounds__(256) void init_bcur(const int* __restrict__ row_ptr,
                                                 int* __restrict__ bcur) {
    int b = blockIdx.x * 256 + threadIdx.x;
    if (b < N_BUCKETS) bcur[b] = row_ptr[b * BK_NODES];
}

// pass 1: block-local bucket scatter. LDS histogram -> ONE global atomic per
// (block,bucket) range reservation -> LDS-cursor placement. Per-address atomic
// chain = SC_BLOCKS (vs 4092 with per-edge atomics: ~135ns per same-addr RMW).
__global__ __launch_bounds__(256) void bucket_scatter(const int* __restrict__ src,
                                                      const int* __restrict__ dst,
                                                      const float* __restrict__ w,
                                                      int* __restrict__ bcur,
                                                      int2* __restrict__ bkt) {
    __shared__ int hist[N_BUCKETS];
    __shared__ int base[N_BUCKETS];
    int tid = threadIdx.x;
    int v0  = blockIdx.x * (EPB / 4);        // int4-chunk base
    const int4*   dst4 = (const int4*)dst;
    const int4*   src4 = (const int4*)src;
    const float4* w4   = (const float4*)w;

    for (int b = tid; b < N_BUCKETS; b += 256) hist[b] = 0;
    __syncthreads();

    // phase A: count buckets (vectorized dst reads)
    for (int v = tid; v < EPB / 4; v += 256) {
        int4 d = dst4[v0 + v];
        atomicAdd(&hist[d.x >> 8], 1);
        atomicAdd(&hist[d.y >> 8], 1);
        atomicAdd(&hist[d.z >> 8], 1);
        atomicAdd(&hist[d.w >> 8], 1);
    }
    __syncthreads();

    // phase B: reserve contiguous ranges, reset hist as local cursor
    for (int b = tid; b < N_BUCKETS; b += 256) {
        int c = hist[b];
        base[b] = (c > 0) ? atomicAdd(&bcur[b], c) : 0;
        hist[b] = 0;
    }
    __syncthreads();

    // phase C: place edges densely inside reserved ranges
    for (int v = tid; v < EPB / 4; v += 256) {
        int4   d = dst4[v0 + v];
        int4   s = src4[v0 + v];
        float4 f = w4[v0 + v];
        {
            int p = base[d.x >> 8] + atomicAdd(&hist[d.x >> 8], 1);
            unsigned wq = (unsigned)rintf(f.x * 32767.0f);
            bkt[p] = make_int2(s.x, (int)(((unsigned)d.x << 15) | wq));
        }
        {
            int p = base[d.y >> 8] + atomicAdd(&hist[d.y >> 8], 1);
            unsigned wq = (unsigned)rintf(f.y * 32767.0f);
            bkt[p] = make_int2(s.y, (int)(((unsigned)d.y << 15) | wq));
        }
        {
            int p = base[d.z >> 8] + atomicAdd(&hist[d.z >> 8], 1);
            unsigned wq = (unsigned)rintf(f.z * 32767.0f);
            bkt[p] = make_int2(s.z, (int)(((unsigned)d.z << 15) | wq));
        }
        {
            int p = base[d.w >> 8] + atomicAdd(&hist[d.w >> 8], 1);
            unsigned wq = (unsigned)rintf(f.w * 32767.0f);
            bkt[p] = make_int2(s.w, (int)(((unsigned)d.w << 15) | wq));
        }
    }
}

// pass 2: one block per bucket; LDS per-node cursors; dense contiguous csr writes.
// csr[p] = (src << 15) | wq
__global__ __launch_bounds__(256) void bucket_to_csr(const int* __restrict__ row_ptr,
                                                     const int2* __restrict__ bkt,
                                                     unsigned* __restrict__ csr) {
    __shared__ int rp_s[BK_NODES];
    __shared__ int cur[BK_NODES];
    int tid   = threadIdx.x;
    int node0 = blockIdx.x * BK_NODES;
    int nN    = N_NODES - node0; if (nN > BK_NODES) nN = BK_NODES;
    if (tid < nN) { rp_s[tid] = row_ptr[node0 + tid]; cur[tid] = 0; }
    __syncthreads();
    int beg  = row_ptr[node0];
    int endv = row_ptr[node0 + nN];
    for (int i = beg + tid; i < endv; i += 256) {
        int2 t = bkt[i];
        unsigned meta = (unsigned)t.y;
        int local = (int)(meta >> 15) - node0;
        int p = rp_s[local] + atomicAdd(&cur[local], 1);
        csr[p] = ((unsigned)t.x << 15) | (meta & 0x7fffu);
    }
}

// ---------------- fp32 -> f16 convert (x only, once) ----------------

__global__ __launch_bounds__(256) void cvt_f32_f16(const float* __restrict__ in,
                                                   f16* __restrict__ out) {
    int i = blockIdx.x * 256 + threadIdx.x;   // grid 6250: 8 elems/thread
    const float4* in4 = (const float4*)in;
    float4 a = in4[i * 2], b = in4[i * 2 + 1];
    f16x8 v;
    v[0] = (f16)a.x; v[1] = (f16)a.y; v[2] = (f16)a.z; v[3] = (f16)a.w;
    v[4] = (f16)b.x; v[5] = (f16)b.y; v[6] = (f16)b.z; v[7] = (f16)b.w;
    ((f16x8*)out)[i] = v;
}

// ---------------- weight pack: B-fragment layout, f16 ----------------
// Bp element ((ks*8 + ct)*64 + lane)*8 + e = W[j][k] with
// j = ct*16 + (lane&15), k = ks*32 + (lane>>4)*8 + e  (k<128 -> Wrel, else Wroot)

__global__ __launch_bounds__(256) void pack_weights(const float* __restrict__ Wrel,
                                                    const float* __restrict__ Wroot,
                                                    f16* __restrict__ Bp) {
    int idx = blockIdx.x * 256 + threadIdx.x;   // 32768 total -> 128 blocks
    int e = idx & 7, lane = (idx >> 3) & 63, ct = (idx >> 9) & 7, ks = idx >> 12;
    int j = ct * 16 + (lane & 15);
    int k = ks * 32 + (lane >> 4) * 8 + e;
    float w = (k < D) ? Wrel[j * D + k] : Wroot[j * D + (k - D)];
    Bp[idx] = (f16)w;
}

// ---------------- aggregation: one wave/node, readlane CSR, pinned 16-deep MLP ----

__global__ __launch_bounds__(256) void aggregate_kernel(const f16* __restrict__ h,
                                                        const int* __restrict__ row_ptr,
                                                        const unsigned* __restrict__ csr,
                                                        f16* __restrict__ agg) {
    int node = blockIdx.x * 4 + (threadIdx.x >> 6);   // grid*4 == N_NODES exactly
    int lane = threadIdx.x & 63;
    int li   = lane & 15;
    int beg = row_ptr[node], end = row_ptr[node + 1];
    const f16x2* h2 = (const f16x2*)h;   // lane covers channels 2l, 2l+1

    float ax0 = 0.f, ay0 = 0.f, ax1 = 0.f, ay1 = 0.f;

    int e = beg;
    for (; e + 16 <= end; e += 16) {
        // lanes 0-15 fetch 16 packed edges in one 64B load (quarters duplicate)
        unsigned pv = csr[e + li];
        __builtin_amdgcn_sched_barrier(0);
        f16x2 gv[16];
        float gw[16];
#pragma unroll
        for (int k = 0; k < 16; ++k) {
            unsigned s = __builtin_amdgcn_readlane(pv, k);   // uniform -> SGPR
            gw[k] = (float)(s & 0x7fffu) * (1.0f / 32767.0f);
            gv[k] = h2[(size_t)(s >> 15) * 64 + lane];       // saddr gather, 256B/wave
        }
        __builtin_amdgcn_sched_barrier(0);   // keep all 16 gathers in flight
#pragma unroll
        for (int k = 0; k < 16; ++k) {
            float vx = (float)gv[k][0], vy = (float)gv[k][1];
            if (k & 1) { ax1 = fmaf(gw[k], vx, ax1); ay1 = fmaf(gw[k], vy, ay1); }
            else       { ax0 = fmaf(gw[k], vx, ax0); ay0 = fmaf(gw[k], vy, ay0); }
        }
    }
    if (e < end) {   // masked tail chunk: clamped index, zeroed weights
        int rem = end - e;
        int idx = e + li, em1 = end - 1;
        idx = idx < em1 ? idx : em1;
        unsigned pv = csr[idx];
        __builtin_amdgcn_sched_barrier(0);
        f16x2 gv[16];
        float gw[16];
#pragma unroll
        for (int k = 0; k < 16; ++k) {
            unsigned s = __builtin_amdgcn_readlane(pv, k);
            gw[k] = (k < rem) ? (float)(s & 0x7fffu) * (1.0f / 32767.0f) : 0.f;
            gv[k] = h2[(size_t)(s >> 15) * 64 + lane];
        }
        __builtin_amdgcn_sched_barrier(0);
#pragma unroll
        for (int k = 0; k < 16; ++k) {
            float vx = (float)gv[k][0], vy = (float)gv[k][1];
            if (k & 1) { ax1 = fmaf(gw[k], vx, ax1); ay1 = fmaf(gw[k], vy, ay1); }
            else       { ax0 = fmaf(gw[k], vx, ax0); ay0 = fmaf(gw[k], vy, ay0); }
        }
    }
    f16x2 o;
    o[0] = (f16)(ax0 + ax1);
    o[1] = (f16)(ay0 + ay1);
    ((f16x2*)agg)[(size_t)node * 64 + lane] = o;
}

// ---------------- MFMA GEMM: out = [agg|h] @ Bp + bias (+ReLU) ----------------
// 256 thr = 4 waves (2 row x 2 col). Wave owns 16 rows x 64 cols.
// B-frags in registers. A (f16) staged in LDS, XOR-swizzled, double-buffered.
// FINAL=0: f16 out + ReLU.  FINAL=1: fp32 out, no ReLU.

template <int FINAL>
__global__ __launch_bounds__(256, 2) void gemm_mfma(const f16* __restrict__ agg,
                                                    const f16* __restrict__ h,
                                                    const f16x8* __restrict__ Bp,
                                                    const float* __restrict__ bias,
                                                    void* __restrict__ outp) {
    __shared__ f16 sA[2][32 * 256];   // 2 x 16 KB
    int tid  = threadIdx.x;
    int lane = tid & 63;
    int wid  = tid >> 6;
    int wrow = wid >> 1;              // rows [wrow*16, +16)
    int wcol = wid & 1;               // cols [wcol*64, +64)

    // B fragments: 8 k-steps x 4 col-tiles, loaded once (L2-hot)
    f16x8 breg[8][4];
#pragma unroll
    for (int ks = 0; ks < 8; ++ks)
#pragma unroll
        for (int c = 0; c < 4; ++c)
            breg[ks][c] = Bp[(ks * 8 + wcol * 4 + c) * 64 + lane];

    float bv[4];
#pragma unroll
    for (int c = 0; c < 4; ++c) bv[c] = bias[wcol * 64 + c * 16 + (lane & 15)];

    const uint4* a16 = (const uint4*)agg;   // 8 f16 per uint4; 16 chunks/row
    const uint4* h16 = (const uint4*)h;

    // prologue: stage first tile into buf 0 (1024 x 16B chunks, 4 iters)
    {
        int row0 = blockIdx.x * 32;
#pragma unroll
        for (int it = 0; it < 4; ++it) {
            int i = it * 256 + tid, r = i >> 5, c8 = i & 31;
            uint4 v = (c8 < 16) ? a16[(row0 + r) * 16 + c8]
                                : h16[(row0 + r) * 16 + (c8 - 16)];
            int o = (r * 256 + c8 * 8) ^ ((r & 7) << 3);
            *(uint4*)&sA[0][o] = v;
        }
    }
    __syncthreads();

    int buf = 0;
    for (int t = blockIdx.x; t < N_TILES; t += GEMM_GRID) {
        int  tn = t + GEMM_GRID;
        bool havenext = (tn < N_TILES);

        // issue next tile's global loads early (latency hides under MFMA)
        uint4 sreg[4];
        if (havenext) {
            int row0 = tn * 32;
#pragma unroll
            for (int it = 0; it < 4; ++it) {
                int i = it * 256 + tid, r = i >> 5, c8 = i & 31;
                sreg[it] = (c8 < 16) ? a16[(row0 + r) * 16 + c8]
                                     : h16[(row0 + r) * 16 + (c8 - 16)];
            }
        }

        // compute tile t from sA[buf]
        f32x4 acc[4] = {f32x4{0,0,0,0}, f32x4{0,0,0,0}, f32x4{0,0,0,0}, f32x4{0,0,0,0}};
        int arow = wrow * 16 + (lane & 15);
        int kg   = (lane >> 4) * 8;
#pragma unroll
        for (int ks = 0; ks < 8; ++ks) {
            int o = (arow * 256 + ks * 32 + kg) ^ ((arow & 7) << 3);
            f16x8 afrag = *(const f16x8*)&sA[buf][o];
#pragma unroll
            for (int c = 0; c < 4; ++c)
                acc[c] = __builtin_amdgcn_mfma_f32_16x16x32_f16(afrag, breg[ks][c],
                                                                acc[c], 0, 0, 0);
        }

        // epilogue: bias (+relu), store C  (C/D map: col=lane&15, row=(lane>>4)*4+r)
        {
            int row0 = t * 32;
#pragma unroll
            for (int c = 0; c < 4; ++c) {
                int col = wcol * 64 + c * 16 + (lane & 15);
#pragma unroll
                for (int r = 0; r < 4; ++r) {
                    int row = row0 + wrow * 16 + (lane >> 4) * 4 + r;
                    float o = acc[c][r] + bv[c];
                    if (FINAL) {
                        ((float*)outp)[(size_t)row * D + col] = o;
                    } else {
                        ((f16*)outp)[(size_t)row * D + col] = (f16)fmaxf(o, 0.f);
                    }
                }
            }
        }

        __syncthreads();   // all waves done reading sA[buf^1] (previous iter)
        if (havenext) {
#pragma unroll
            for (int it = 0; it < 4; ++it) {
                int i = it * 256 + tid, r = i >> 5, c8 = i & 31;
                int o = (r * 256 + c8 * 8) ^ ((r & 7) << 3);
                *(uint4*)&sA[buf ^ 1][o] = sreg[it];
            }
        }
        __syncthreads();
        buf ^= 1;
    }
}

// ---------------- launch ----------------

extern "C" void kernel_launch(void* const* d_in, const int* in_sizes, int n_in,
                              void* d_out, int out_size, void* d_ws, size_t ws_size,
                              hipStream_t stream) {
    const float* x  = (const float*)d_in[0];
    const float* ew = (const float*)d_in[1];
    const float* W_rel[3]  = {(const float*)d_in[2], (const float*)d_in[5], (const float*)d_in[8]};
    const float* W_root[3] = {(const float*)d_in[3], (const float*)d_in[6], (const float*)d_in[9]};
    const float* bias[3]   = {(const float*)d_in[4], (const float*)d_in[7], (const float*)d_in[10]};
    const int* esrc = (const int*)d_in[11];
    const int* edst = (const int*)d_in[12];

    char* ws = (char*)d_ws;
    f16*      agg16     = (f16*)     (ws);               // 25,600,000 B
    f16*      bufA      = (f16*)     (ws + 25600000);    // 25,600,000 B
    f16*      bufB      = (f16*)     (ws + 51200000);    // 25,600,000 B
    unsigned* csr       = (unsigned*)(ws + 76800000);    //  6,400,000 B
    int2*     bkt       = (int2*)    (ws + 83200000);    // 12,800,000 B
    int*      row_ptr   = (int*)     (ws + 96000000);    //    400,016 B
    int*      cnt       = (int*)     (ws + 96400016);    //    400,000 B
    int*      blockSums = (int*)     (ws + 96800016);    //        512 B
    int*      bcur      = (int*)     (ws + 96800528);    //      1,564 B
    f16*      Bp        = (f16*)     (ws + 96802092);    //    196,608 B

    // CSR build (reused by all 3 layers)
    hipMemsetAsync(cnt, 0, N_NODES * sizeof(int), stream);
    hist_kernel<<<N_EDGES / 256, 256, 0, stream>>>(edst, cnt);
    scanA<<<98, 256, 0, stream>>>(cnt, row_ptr, blockSums);
    scanB<<<1, 64, 0, stream>>>(blockSums, 98);
    scanC<<<98, 256, 0, stream>>>(row_ptr, blockSums);
    init_bcur<<<2, 256, 0, stream>>>(row_ptr, bcur);
    bucket_scatter<<<SC_BLOCKS, 256, 0, stream>>>(esrc, edst, ew, bcur, bkt);
    bucket_to_csr<<<N_BUCKETS, 256, 0, stream>>>(row_ptr, bkt, csr);

    // x -> f16, weight packs
    cvt_f32_f16<<<6250, 256, 0, stream>>>(x, bufA);
    for (int l = 0; l < 3; ++l)
        pack_weights<<<128, 256, 0, stream>>>(W_rel[l], W_root[l], Bp + l * 32768);

    // layer 0: bufA -> bufB (f16, relu)
    aggregate_kernel<<<N_NODES / 4, 256, 0, stream>>>(bufA, row_ptr, csr, agg16);
    gemm_mfma<0><<<GEMM_GRID, 256, 0, stream>>>(agg16, bufA, (const f16x8*)(Bp + 0 * 32768),
                                                bias[0], bufB);
    // layer 1: bufB -> bufA (f16, relu)
    aggregate_kernel<<<N_NODES / 4, 256, 0, stream>>>(bufB, row_ptr, csr, agg16);
    gemm_mfma<0><<<GEMM_GRID, 256, 0, stream>>>(agg16, bufB, (const f16x8*)(Bp + 1 * 32768),
                                                bias[1], bufA);
    // layer 2: bufA -> d_out (fp32, no relu)
    aggregate_kernel<<<N_NODES / 4, 256, 0, stream>>>(bufA, row_ptr, csr, agg16);
    gemm_mfma<1><<<GEMM_GRID, 256, 0, stream>>>(agg16, bufA, (const f16x8*)(Bp + 2 * 32768),
                                                bias[2], d_out);
}

// Round 8
// 310.291 us; speedup vs baseline: 2.9856x; 1.2624x over previous
//
#include <hip/hip_runtime.h>

#define N_NODES 100000
#define N_EDGES 1600000
#define D 128
#define N_TILES 3125        // N_NODES / 32
#define GEMM_GRID 512
#define BK_NODES 256        // nodes per bucket
#define N_BUCKETS 391       // ceil(N_NODES / BK_NODES)
#define BKT_CAP 5120        // per-bucket slot capacity (mean 4092, std 64 -> 16 sigma)
#define SC_BLOCKS 128
#define EPB 12500           // edges per scatter block (N_EDGES / SC_BLOCKS)

typedef _Float16 f16;
typedef _Float16 f16x8 __attribute__((ext_vector_type(8)));
typedef _Float16 f16x2 __attribute__((ext_vector_type(2)));
typedef float f32x4 __attribute__((ext_vector_type(4)));

// ---------------- CSR build (bucket-based, no per-node global atomics) ----------------

// pass 1: block-local bucket scatter. LDS histogram -> ONE global atomic per
// (block,bucket) reservation (chain length = SC_BLOCKS) -> LDS-cursor placement
// into fixed-capacity bucket slots. Afterwards bcur[b] == bucket edge count.
__global__ __launch_bounds__(256) void bucket_scatter(const int* __restrict__ src,
                                                      const int* __restrict__ dst,
                                                      const float* __restrict__ w,
                                                      int* __restrict__ bcur,
                                                      int2* __restrict__ bkt) {
    __shared__ int hist[N_BUCKETS];
    __shared__ int base[N_BUCKETS];
    int tid = threadIdx.x;
    int v0  = blockIdx.x * (EPB / 4);        // int4-chunk base
    const int4*   dst4 = (const int4*)dst;
    const int4*   src4 = (const int4*)src;
    const float4* w4   = (const float4*)w;

    for (int b = tid; b < N_BUCKETS; b += 256) hist[b] = 0;
    __syncthreads();

    // phase A: count buckets (vectorized dst reads)
    for (int v = tid; v < EPB / 4; v += 256) {
        int4 d = dst4[v0 + v];
        atomicAdd(&hist[d.x >> 8], 1);
        atomicAdd(&hist[d.y >> 8], 1);
        atomicAdd(&hist[d.z >> 8], 1);
        atomicAdd(&hist[d.w >> 8], 1);
    }
    __syncthreads();

    // phase B: reserve within-bucket ranges (bcur starts at 0)
    for (int b = tid; b < N_BUCKETS; b += 256) {
        int c = hist[b];
        base[b] = b * BKT_CAP + ((c > 0) ? atomicAdd(&bcur[b], c) : 0);
        hist[b] = 0;
    }
    __syncthreads();

    // phase C: place edges densely inside reserved ranges
    for (int v = tid; v < EPB / 4; v += 256) {
        int4   d = dst4[v0 + v];
        int4   s = src4[v0 + v];
        float4 f = w4[v0 + v];
        {
            int p = base[d.x >> 8] + atomicAdd(&hist[d.x >> 8], 1);
            unsigned wq = (unsigned)rintf(f.x * 32767.0f);
            bkt[p] = make_int2(s.x, (int)(((unsigned)d.x << 15) | wq));
        }
        {
            int p = base[d.y >> 8] + atomicAdd(&hist[d.y >> 8], 1);
            unsigned wq = (unsigned)rintf(f.y * 32767.0f);
            bkt[p] = make_int2(s.y, (int)(((unsigned)d.y << 15) | wq));
        }
        {
            int p = base[d.z >> 8] + atomicAdd(&hist[d.z >> 8], 1);
            unsigned wq = (unsigned)rintf(f.z * 32767.0f);
            bkt[p] = make_int2(s.z, (int)(((unsigned)d.z << 15) | wq));
        }
        {
            int p = base[d.w >> 8] + atomicAdd(&hist[d.w >> 8], 1);
            unsigned wq = (unsigned)rintf(f.w * 32767.0f);
            bkt[p] = make_int2(s.w, (int)(((unsigned)d.w << 15) | wq));
        }
    }
}

// exclusive scan over the 391 bucket counts -> bucket CSR bases (one block)
__global__ __launch_bounds__(512) void bucket_scan(const int* __restrict__ bcnt,
                                                   int* __restrict__ bbase) {
    __shared__ int sc[512];
    int tid = threadIdx.x;
    int v = (tid < N_BUCKETS) ? bcnt[tid] : 0;
    sc[tid] = v;
    __syncthreads();
    for (int off = 1; off < 512; off <<= 1) {
        int t = (tid >= off) ? sc[tid - off] : 0;
        __syncthreads();
        sc[tid] += t;
        __syncthreads();
    }
    if (tid < N_BUCKETS) bbase[tid] = sc[tid] - v;
}

// pass 2: one block per bucket. LDS node histogram + block scan -> row_ptr AND
// final csr placement (dense contiguous writes). csr[p] = (src << 15) | wq.
__global__ __launch_bounds__(256) void bucket_finalize(const int* __restrict__ bcnt,
                                                       const int* __restrict__ bbase,
                                                       const int2* __restrict__ bkt,
                                                       unsigned* __restrict__ csr,
                                                       int* __restrict__ row_ptr) {
    __shared__ int ncnt[BK_NODES];
    __shared__ int noff[BK_NODES];
    __shared__ int sc[BK_NODES];
    int tid   = threadIdx.x;
    int b     = blockIdx.x;
    int node0 = b * BK_NODES;
    int cnt   = bcnt[b];
    int base  = bbase[b];
    int e0    = b * BKT_CAP;

    ncnt[tid] = 0;
    __syncthreads();
    for (int i = tid; i < cnt; i += 256) {
        int local = (int)((unsigned)bkt[e0 + i].y >> 15) - node0;
        atomicAdd(&ncnt[local], 1);
    }
    __syncthreads();
    // exclusive scan of ncnt
    int s = ncnt[tid];
    sc[tid] = s;
    __syncthreads();
    for (int off = 1; off < 256; off <<= 1) {
        int t = (tid >= off) ? sc[tid - off] : 0;
        __syncthreads();
        sc[tid] += t;
        __syncthreads();
    }
    noff[tid] = sc[tid] - s;
    ncnt[tid] = 0;   // reuse as placement cursor
    {
        int nN = N_NODES - node0; if (nN > BK_NODES) nN = BK_NODES;
        if (tid < nN) row_ptr[node0 + tid] = base + noff[tid];
        if (b == N_BUCKETS - 1 && tid == 0) row_ptr[N_NODES] = N_EDGES;
    }
    __syncthreads();
    for (int i = tid; i < cnt; i += 256) {
        int2 t = bkt[e0 + i];
        unsigned meta = (unsigned)t.y;
        int local = (int)(meta >> 15) - node0;
        int p = base + noff[local] + atomicAdd(&ncnt[local], 1);
        csr[p] = ((unsigned)t.x << 15) | (meta & 0x7fffu);
    }
}

// ---------------- fp32 -> f16 convert (x only, once) ----------------

__global__ __launch_bounds__(256) void cvt_f32_f16(const float* __restrict__ in,
                                                   f16* __restrict__ out) {
    int i = blockIdx.x * 256 + threadIdx.x;   // grid 6250: 8 elems/thread
    const float4* in4 = (const float4*)in;
    float4 a = in4[i * 2], b = in4[i * 2 + 1];
    f16x8 v;
    v[0] = (f16)a.x; v[1] = (f16)a.y; v[2] = (f16)a.z; v[3] = (f16)a.w;
    v[4] = (f16)b.x; v[5] = (f16)b.y; v[6] = (f16)b.z; v[7] = (f16)b.w;
    ((f16x8*)out)[i] = v;
}

// ---------------- weight pack: B-fragment layout, f16 ----------------
// Bp element ((ks*8 + ct)*64 + lane)*8 + e = W[j][k] with
// j = ct*16 + (lane&15), k = ks*32 + (lane>>4)*8 + e  (k<128 -> Wrel, else Wroot)

__global__ __launch_bounds__(256) void pack_weights(const float* __restrict__ Wrel,
                                                    const float* __restrict__ Wroot,
                                                    f16* __restrict__ Bp) {
    int idx = blockIdx.x * 256 + threadIdx.x;   // 32768 total -> 128 blocks
    int e = idx & 7, lane = (idx >> 3) & 63, ct = (idx >> 9) & 7, ks = idx >> 12;
    int j = ct * 16 + (lane & 15);
    int k = ks * 32 + (lane >> 4) * 8 + e;
    float w = (k < D) ? Wrel[j * D + k] : Wroot[j * D + (k - D)];
    Bp[idx] = (f16)w;
}

// ---------------- aggregation: one wave/node, readlane CSR, pinned 16-deep MLP ----

__global__ __launch_bounds__(256) void aggregate_kernel(const f16* __restrict__ h,
                                                        const int* __restrict__ row_ptr,
                                                        const unsigned* __restrict__ csr,
                                                        f16* __restrict__ agg) {
    int node = blockIdx.x * 4 + (threadIdx.x >> 6);   // grid*4 == N_NODES exactly
    int lane = threadIdx.x & 63;
    int li   = lane & 15;
    int beg = row_ptr[node], end = row_ptr[node + 1];
    const f16x2* h2 = (const f16x2*)h;   // lane covers channels 2l, 2l+1

    float ax0 = 0.f, ay0 = 0.f, ax1 = 0.f, ay1 = 0.f;

    int e = beg;
    for (; e + 16 <= end; e += 16) {
        // lanes 0-15 fetch 16 packed edges in one 64B load (quarters duplicate)
        unsigned pv = csr[e + li];
        __builtin_amdgcn_sched_barrier(0);
        f16x2 gv[16];
        float gw[16];
#pragma unroll
        for (int k = 0; k < 16; ++k) {
            unsigned s = __builtin_amdgcn_readlane(pv, k);   // uniform -> SGPR
            gw[k] = (float)(s & 0x7fffu) * (1.0f / 32767.0f);
            gv[k] = h2[(size_t)(s >> 15) * 64 + lane];       // saddr gather, 256B/wave
        }
        __builtin_amdgcn_sched_barrier(0);   // keep all 16 gathers in flight
#pragma unroll
        for (int k = 0; k < 16; ++k) {
            float vx = (float)gv[k][0], vy = (float)gv[k][1];
            if (k & 1) { ax1 = fmaf(gw[k], vx, ax1); ay1 = fmaf(gw[k], vy, ay1); }
            else       { ax0 = fmaf(gw[k], vx, ax0); ay0 = fmaf(gw[k], vy, ay0); }
        }
    }
    if (e < end) {   // masked tail chunk: clamped index, zeroed weights
        int rem = end - e;
        int idx = e + li, em1 = end - 1;
        idx = idx < em1 ? idx : em1;
        unsigned pv = csr[idx];
        __builtin_amdgcn_sched_barrier(0);
        f16x2 gv[16];
        float gw[16];
#pragma unroll
        for (int k = 0; k < 16; ++k) {
            unsigned s = __builtin_amdgcn_readlane(pv, k);
            gw[k] = (k < rem) ? (float)(s & 0x7fffu) * (1.0f / 32767.0f) : 0.f;
            gv[k] = h2[(size_t)(s >> 15) * 64 + lane];
        }
        __builtin_amdgcn_sched_barrier(0);
#pragma unroll
        for (int k = 0; k < 16; ++k) {
            float vx = (float)gv[k][0], vy = (float)gv[k][1];
            if (k & 1) { ax1 = fmaf(gw[k], vx, ax1); ay1 = fmaf(gw[k], vy, ay1); }
            else       { ax0 = fmaf(gw[k], vx, ax0); ay0 = fmaf(gw[k], vy, ay0); }
        }
    }
    f16x2 o;
    o[0] = (f16)(ax0 + ax1);
    o[1] = (f16)(ay0 + ay1);
    ((f16x2*)agg)[(size_t)node * 64 + lane] = o;
}

// ---------------- MFMA GEMM: out = [agg|h] @ Bp + bias (+ReLU) ----------------
// 256 thr = 4 waves (2 row x 2 col). Wave owns 16 rows x 64 cols.
// B-frags in registers. A (f16) staged in LDS, XOR-swizzled, double-buffered.
// FINAL=0: f16 out + ReLU.  FINAL=1: fp32 out, no ReLU.

template <int FINAL>
__global__ __launch_bounds__(256, 2) void gemm_mfma(const f16* __restrict__ agg,
                                                    const f16* __restrict__ h,
                                                    const f16x8* __restrict__ Bp,
                                                    const float* __restrict__ bias,
                                                    void* __restrict__ outp) {
    __shared__ f16 sA[2][32 * 256];   // 2 x 16 KB
    int tid  = threadIdx.x;
    int lane = tid & 63;
    int wid  = tid >> 6;
    int wrow = wid >> 1;              // rows [wrow*16, +16)
    int wcol = wid & 1;               // cols [wcol*64, +64)

    // B fragments: 8 k-steps x 4 col-tiles, loaded once (L2-hot)
    f16x8 breg[8][4];
#pragma unroll
    for (int ks = 0; ks < 8; ++ks)
#pragma unroll
        for (int c = 0; c < 4; ++c)
            breg[ks][c] = Bp[(ks * 8 + wcol * 4 + c) * 64 + lane];

    float bv[4];
#pragma unroll
    for (int c = 0; c < 4; ++c) bv[c] = bias[wcol * 64 + c * 16 + (lane & 15)];

    const uint4* a16 = (const uint4*)agg;   // 8 f16 per uint4; 16 chunks/row
    const uint4* h16 = (const uint4*)h;

    // prologue: stage first tile into buf 0 (1024 x 16B chunks, 4 iters)
    {
        int row0 = blockIdx.x * 32;
#pragma unroll
        for (int it = 0; it < 4; ++it) {
            int i = it * 256 + tid, r = i >> 5, c8 = i & 31;
            uint4 v = (c8 < 16) ? a16[(row0 + r) * 16 + c8]
                                : h16[(row0 + r) * 16 + (c8 - 16)];
            int o = (r * 256 + c8 * 8) ^ ((r & 7) << 3);
            *(uint4*)&sA[0][o] = v;
        }
    }
    __syncthreads();

    int buf = 0;
    for (int t = blockIdx.x; t < N_TILES; t += GEMM_GRID) {
        int  tn = t + GEMM_GRID;
        bool havenext = (tn < N_TILES);

        // issue next tile's global loads early (latency hides under MFMA)
        uint4 sreg[4];
        if (havenext) {
            int row0 = tn * 32;
#pragma unroll
            for (int it = 0; it < 4; ++it) {
                int i = it * 256 + tid, r = i >> 5, c8 = i & 31;
                sreg[it] = (c8 < 16) ? a16[(row0 + r) * 16 + c8]
                                     : h16[(row0 + r) * 16 + (c8 - 16)];
            }
        }

        // compute tile t from sA[buf]
        f32x4 acc[4] = {f32x4{0,0,0,0}, f32x4{0,0,0,0}, f32x4{0,0,0,0}, f32x4{0,0,0,0}};
        int arow = wrow * 16 + (lane & 15);
        int kg   = (lane >> 4) * 8;
#pragma unroll
        for (int ks = 0; ks < 8; ++ks) {
            int o = (arow * 256 + ks * 32 + kg) ^ ((arow & 7) << 3);
            f16x8 afrag = *(const f16x8*)&sA[buf][o];
#pragma unroll
            for (int c = 0; c < 4; ++c)
                acc[c] = __builtin_amdgcn_mfma_f32_16x16x32_f16(afrag, breg[ks][c],
                                                                acc[c], 0, 0, 0);
        }

        // epilogue: bias (+relu), store C  (C/D map: col=lane&15, row=(lane>>4)*4+r)
        {
            int row0 = t * 32;
#pragma unroll
            for (int c = 0; c < 4; ++c) {
                int col = wcol * 64 + c * 16 + (lane & 15);
#pragma unroll
                for (int r = 0; r < 4; ++r) {
                    int row = row0 + wrow * 16 + (lane >> 4) * 4 + r;
                    float o = acc[c][r] + bv[c];
                    if (FINAL) {
                        ((float*)outp)[(size_t)row * D + col] = o;
                    } else {
                        ((f16*)outp)[(size_t)row * D + col] = (f16)fmaxf(o, 0.f);
                    }
                }
            }
        }

        __syncthreads();   // all waves done reading sA[buf^1] (previous iter)
        if (havenext) {
#pragma unroll
            for (int it = 0; it < 4; ++it) {
                int i = it * 256 + tid, r = i >> 5, c8 = i & 31;
                int o = (r * 256 + c8 * 8) ^ ((r & 7) << 3);
                *(uint4*)&sA[buf ^ 1][o] = sreg[it];
            }
        }
        __syncthreads();
        buf ^= 1;
    }
}

// ---------------- launch ----------------

extern "C" void kernel_launch(void* const* d_in, const int* in_sizes, int n_in,
                              void* d_out, int out_size, void* d_ws, size_t ws_size,
                              hipStream_t stream) {
    const float* x  = (const float*)d_in[0];
    const float* ew = (const float*)d_in[1];
    const float* W_rel[3]  = {(const float*)d_in[2], (const float*)d_in[5], (const float*)d_in[8]};
    const float* W_root[3] = {(const float*)d_in[3], (const float*)d_in[6], (const float*)d_in[9]};
    const float* bias[3]   = {(const float*)d_in[4], (const float*)d_in[7], (const float*)d_in[10]};
    const int* esrc = (const int*)d_in[11];
    const int* edst = (const int*)d_in[12];

    char* ws = (char*)d_ws;
    f16*      agg16   = (f16*)     (ws);               // 25,600,000 B
    f16*      bufA    = (f16*)     (ws + 25600000);    // 25,600,000 B
    f16*      bufB    = (f16*)     (ws + 51200000);    // 25,600,000 B
    unsigned* csr     = (unsigned*)(ws + 76800000);    //  6,400,000 B
    int2*     bkt     = (int2*)    (ws + 83200000);    // 16,015,360 B (391 x 5120 x 8)
    int*      row_ptr = (int*)     (ws + 99215360);    //    400,016 B
    int*      bcur    = (int*)     (ws + 99615376);    //      1,564 B
    int*      bbase   = (int*)     (ws + 99616940);    //      1,564 B
    f16*      Bp      = (f16*)     (ws + 99618504);    //    196,608 B

    // CSR build (bucket-based; reused by all 3 layers)
    hipMemsetAsync(bcur, 0, N_BUCKETS * sizeof(int), stream);
    bucket_scatter<<<SC_BLOCKS, 256, 0, stream>>>(esrc, edst, ew, bcur, bkt);
    bucket_scan<<<1, 512, 0, stream>>>(bcur, bbase);
    bucket_finalize<<<N_BUCKETS, 256, 0, stream>>>(bcur, bbase, bkt, csr, row_ptr);

    // x -> f16, weight packs
    cvt_f32_f16<<<6250, 256, 0, stream>>>(x, bufA);
    for (int l = 0; l < 3; ++l)
        pack_weights<<<128, 256, 0, stream>>>(W_rel[l], W_root[l], Bp + l * 32768);

    // layer 0: bufA -> bufB (f16, relu)
    aggregate_kernel<<<N_NODES / 4, 256, 0, stream>>>(bufA, row_ptr, csr, agg16);
    gemm_mfma<0><<<GEMM_GRID, 256, 0, stream>>>(agg16, bufA, (const f16x8*)(Bp + 0 * 32768),
                                                bias[0], bufB);
    // layer 1: bufB -> bufA (f16, relu)
    aggregate_kernel<<<N_NODES / 4, 256, 0, stream>>>(bufB, row_ptr, csr, agg16);
    gemm_mfma<0><<<GEMM_GRID, 256, 0, stream>>>(agg16, bufB, (const f16x8*)(Bp + 1 * 32768),
                                                bias[1], bufA);
    // layer 2: bufA -> d_out (fp32, no relu)
    aggregate_kernel<<<N_NODES / 4, 256, 0, stream>>>(bufA, row_ptr, csr, agg16);
    gemm_mfma<1><<<GEMM_GRID, 256, 0, stream>>>(agg16, bufA, (const f16x8*)(Bp + 2 * 32768),
                                                bias[2], d_out);
}